// Round 7
// baseline (2100.925 us; speedup 1.0000x reference)
//
#include <hip/hip_runtime.h>

#define N_NODES_C 100000
#define N_EDGES_C 1600000
#define NPB 256                   // partition blocks
#define CH (N_EDGES_C / NPB)      // 6250 edges/partition block (exact)
#define BUCK_SH 7
#define BUCK_NODES 128
#define NB_BUCK 782               // ceil(100000 / 128)

typedef short short8 __attribute__((ext_vector_type(8)));
typedef float f32x4 __attribute__((ext_vector_type(4)));

// float -> bf16 bits (RNE)
__device__ __forceinline__ short f2bf(float f) {
  unsigned u = __builtin_bit_cast(unsigned, f);
  unsigned r = (u + 0x7FFFu + ((u >> 16) & 1u)) >> 16;
  return (short)r;
}
__device__ __forceinline__ float bf2f(unsigned short u) {
  return __builtin_bit_cast(float, (unsigned)u << 16);
}

// ---------------------------------------------------------------------------
// MFMA GEMM body: out[n][64] = in[n][K] @ W[K][64]
// 4 waves/block, each wave a 16x64 tile via 4 n-tiles of mfma 16x16x32_bf16.
// Layouts (verified): A: row=lane&15, k=(lane>>4)*8+j; B: col=lane&15, same k;
// C/D: col=lane&15, row=(lane>>4)*4+reg.
// ---------------------------------------------------------------------------
template <int K, bool IN_BF, bool OUT_BF>
__device__ __forceinline__ void gemm64_body(
    int gblock, const void* __restrict__ in_, const float* __restrict__ W,
    void* __restrict__ out_, int n_rows) {
  constexpr int KS = K / 32;
  int wave = threadIdx.x >> 6;
  int lane = threadIdx.x & 63;
  int row0 = (gblock * 4 + wave) * 16;
  if (row0 >= n_rows) return;  // n_rows % 16 == 0 -> full tiles only

  int lrow = lane & 15;
  int lk = (lane >> 4) * 8;

  short8 bfrag[KS][4];
#pragma unroll
  for (int ks = 0; ks < KS; ++ks)
#pragma unroll
    for (int nt = 0; nt < 4; ++nt) {
      short8 b;
#pragma unroll
      for (int j = 0; j < 8; ++j)
        b[j] = f2bf(W[(size_t)(ks * 32 + lk + j) * 64 + nt * 16 + lrow]);
      bfrag[ks][nt] = b;
    }

  int row = row0 + lrow;
  f32x4 acc[4] = {};
#pragma unroll
  for (int ks = 0; ks < KS; ++ks) {
    short8 a;
    if constexpr (IN_BF) {
      const short* ip = (const short*)in_ + (size_t)row * K + ks * 32 + lk;
      a = *(const short8*)ip;
    } else {
      const float* ip = (const float*)in_ + (size_t)row * K + ks * 32 + lk;
      f32x4 v0 = *(const f32x4*)(ip);
      f32x4 v1 = *(const f32x4*)(ip + 4);
#pragma unroll
      for (int j = 0; j < 4; ++j) {
        a[j] = f2bf(v0[j]);
        a[4 + j] = f2bf(v1[j]);
      }
    }
#pragma unroll
    for (int nt = 0; nt < 4; ++nt)
      acc[nt] = __builtin_amdgcn_mfma_f32_16x16x32_bf16(a, bfrag[ks][nt],
                                                        acc[nt], 0, 0, 0);
  }

  int crow = row0 + (lane >> 4) * 4;
#pragma unroll
  for (int nt = 0; nt < 4; ++nt) {
    int ocol = nt * 16 + lrow;
#pragma unroll
    for (int r = 0; r < 4; ++r) {
      if constexpr (OUT_BF)
        ((short*)out_)[(size_t)(crow + r) * 64 + ocol] = f2bf(acc[nt][r]);
      else
        ((float*)out_)[(size_t)(crow + r) * 64 + ocol] = acc[nt][r];
    }
  }
}

template <int K, bool IN_BF, bool OUT_BF>
__global__ __launch_bounds__(256) void mfma_gemm64(
    const void* __restrict__ in_, const float* __restrict__ W,
    void* __restrict__ out_, int n_rows) {
  gemm64_body<K, IN_BF, OUT_BF>(blockIdx.x, in_, W, out_, n_rows);
}

// ---------------------------------------------------------------------------
// Fused: blocks [0, gemm_blocks) = GEMM1 (x@W1 -> hA bf16).
// Blocks [gemm_blocks, +NPB) = bucket histogram of its edge chunk via LDS
// int atomics (zero global atomics), written to countsT[bucket][blk].
// ---------------------------------------------------------------------------
__global__ __launch_bounds__(256) void hist_gemm1_kernel(
    const float* __restrict__ x, const float* __restrict__ W1,
    short* __restrict__ hA, int n_rows, int gemm_blocks,
    const int* __restrict__ dst, int* __restrict__ countsT) {
  __shared__ int lhist[NB_BUCK];
  int b = (int)blockIdx.x;
  if (b < gemm_blocks) {
    gemm64_body<128, false, true>(b, x, W1, hA, n_rows);
    return;
  }
  int cb = b - gemm_blocks;
  for (int i = threadIdx.x; i < NB_BUCK; i += 256) lhist[i] = 0;
  __syncthreads();
  int beg = cb * CH, end = beg + CH;
  for (int i = beg + (int)threadIdx.x; i < end; i += 256)
    atomicAdd(&lhist[((unsigned)dst[i]) >> BUCK_SH], 1);
  __syncthreads();
  for (int bb = threadIdx.x; bb < NB_BUCK; bb += 256)
    countsT[bb * NPB + cb] = lhist[bb];
}

// ---------------------------------------------------------------------------
// K1: per-bucket exclusive scan over the NPB=256 per-block counts (in place)
// + bucket total. One wave per bucket; lane holds 4 values (int4).
// ---------------------------------------------------------------------------
__global__ __launch_bounds__(256) void scan_buckets_kernel(
    int* __restrict__ countsT, int* __restrict__ btot) {
  int b = blockIdx.x * 4 + (threadIdx.x >> 6);
  int lane = threadIdx.x & 63;
  if (b >= NB_BUCK) return;
  int4 v = *(const int4*)(countsT + b * NPB + lane * 4);
  int s = v.x + v.y + v.z + v.w;
  int incl = s;
#pragma unroll
  for (int d = 1; d < 64; d <<= 1) {
    int t = __shfl_up(incl, d, 64);
    if (lane >= d) incl += t;
  }
  int excl = incl - s;
  int4 o;
  o.x = excl;
  o.y = excl + v.x;
  o.z = o.y + v.y;
  o.w = o.z + v.z;
  *(int4*)(countsT + b * NPB + lane * 4) = o;
  if (lane == 63) btot[b] = incl;
}

// K2: exclusive scan of the 782 bucket totals -> bstart[0..NB_BUCK].
__global__ __launch_bounds__(1024) void scan_btot_kernel(
    const int* __restrict__ btot, int* __restrict__ bstart) {
  __shared__ int lds[1024];
  int t = threadIdx.x;
  int v = (t < NB_BUCK) ? btot[t] : 0;
  lds[t] = v;
  __syncthreads();
  for (int off = 1; off < 1024; off <<= 1) {
    int tv = (t >= off) ? lds[t - off] : 0;
    __syncthreads();
    lds[t] += tv;
    __syncthreads();
  }
  if (t < NB_BUCK) bstart[t] = lds[t] - v;
  if (t == NB_BUCK - 1) bstart[NB_BUCK] = lds[t];
}

// ---------------------------------------------------------------------------
// Partition pass B: scatter packed edge words ((ldst<<17)|src) into bucket
// order. LDS cursors (782), LDS atomics only; writes have bucket locality.
// ---------------------------------------------------------------------------
__global__ __launch_bounds__(256) void partition_kernel(
    const int* __restrict__ src, const int* __restrict__ dst,
    const int* __restrict__ offs /* = countsT after K1 */,
    const int* __restrict__ bstart, unsigned* __restrict__ packed) {
  __shared__ int cur[NB_BUCK];
  int blk = (int)blockIdx.x;
  for (int bb = threadIdx.x; bb < NB_BUCK; bb += 256)
    cur[bb] = bstart[bb] + offs[bb * NPB + blk];
  __syncthreads();
  int beg = blk * CH, end = beg + CH;
  for (int i = beg + (int)threadIdx.x; i < end; i += 256) {
    int d = dst[i];
    int s = src[i];
    int bb = ((unsigned)d) >> BUCK_SH;
    int pos = atomicAdd(&cur[bb], 1);
    packed[pos] = ((unsigned)(d & (BUCK_NODES - 1)) << 17) | (unsigned)s;
  }
}

// ---------------------------------------------------------------------------
// Bucket aggregation + bias + ReLU. Block = one bucket of 128 nodes; LDS
// f32 accumulator [128][64] (32 KB). 8 waves; lane = channel; each wave
// streams 4 edges at a time: gather 128B bf16 row of h[src], ds_add_f32
// into acc[ldst*64+lane] (2 lanes/bank -> conflict-free). Epilogue:
// bias+relu, store bf16 (hidden) or f32 (final).
// ---------------------------------------------------------------------------
template <bool OUT_BF>
__global__ __launch_bounds__(512) void agg_bucket_kernel(
    const unsigned short* __restrict__ h, const unsigned* __restrict__ packed,
    const int* __restrict__ bstart, const float* __restrict__ bias,
    void* __restrict__ out, int n_nodes) {
  __shared__ float acc[BUCK_NODES * 64];
  for (int i = threadIdx.x; i < BUCK_NODES * 64; i += 512) acc[i] = 0.f;
  __syncthreads();

  int b = (int)blockIdx.x;
  int beg = bstart[b], end = bstart[b + 1];
  int w = __builtin_amdgcn_readfirstlane(threadIdx.x >> 6);
  int lane = threadIdx.x & 63;

  for (int base = beg + w * 4; base < end; base += 32) {
    float v[4];
    int ld[4];
#pragma unroll
    for (int j = 0; j < 4; ++j) {
      int e = base + j;
      if (e < end) {
        unsigned pe = packed[e];
        ld[j] = (int)(pe >> 17);
        v[j] = bf2f(h[(size_t)(pe & 0x1FFFFu) * 64 + lane]);
      } else {
        ld[j] = -1;
        v[j] = 0.f;
      }
    }
#pragma unroll
    for (int j = 0; j < 4; ++j)
      if (ld[j] >= 0) atomicAdd(&acc[ld[j] * 64 + lane], v[j]);
  }
  __syncthreads();

  int node0 = b * BUCK_NODES;
  for (int i = threadIdx.x; i < BUCK_NODES * 64; i += 512) {
    int node = node0 + (i >> 6);
    if (node < n_nodes) {
      int c = i & 63;
      float r = fmaxf(acc[i] + bias[c], 0.f);
      if constexpr (OUT_BF)
        ((unsigned short*)out)[(size_t)node * 64 + c] = (unsigned short)f2bf(r);
      else
        ((float*)out)[(size_t)node * 64 + c] = r;
    }
  }
}

extern "C" void kernel_launch(void* const* d_in, const int* in_sizes, int n_in,
                              void* d_out, int out_size, void* d_ws,
                              size_t ws_size, hipStream_t stream) {
  const float* x = (const float*)d_in[0];
  const int* src = (const int*)d_in[1];
  const int* dst = (const int*)d_in[2];
  const float* W1 = (const float*)d_in[3];
  const float* b1 = (const float*)d_in[4];
  const float* W2 = (const float*)d_in[5];
  const float* b2 = (const float*)d_in[6];
  const float* W3 = (const float*)d_in[7];
  const float* b3 = (const float*)d_in[8];
  float* out = (float*)d_out;

  const int N = N_NODES_C;

  // Workspace layout (35 MB):
  //   [0, 1MB)    countsT[NB_BUCK][NPB]  (800 KB; becomes offs after K1)
  //   [1MB, +4KB) btot (782 ints)
  //   [1MB+16KB)  bstart (783 ints)
  //   [2MB, 9MB)  packed edges (E u32 = 6.4 MB)
  //   [9, 22MB)   hA (N*64 bf16)
  //   [22, 35MB)  hB (N*64 bf16)
  char* ws = (char*)d_ws;
  int* countsT = (int*)(ws + 0);
  int* btot = (int*)(ws + (1u << 20));
  int* bstart = (int*)(ws + (1u << 20) + (16u << 10));
  unsigned* packed = (unsigned*)(ws + (2u << 20));
  short* hA = (short*)(ws + (9u << 20));
  short* hB = (short*)(ws + (22u << 20));

  const int gemm_grid = (N + 63) / 64;  // 1563
  const int k1_grid = (NB_BUCK + 3) / 4;

  // ---- GEMM1 ∥ bucket histogram ----
  hist_gemm1_kernel<<<gemm_grid + NPB, 256, 0, stream>>>(x, W1, hA, N,
                                                         gemm_grid, dst,
                                                         countsT);
  scan_buckets_kernel<<<k1_grid, 256, 0, stream>>>(countsT, btot);
  scan_btot_kernel<<<1, 1024, 0, stream>>>(btot, bstart);
  partition_kernel<<<NPB, 256, 0, stream>>>(src, dst, countsT, bstart, packed);

  // ---- Layer 1 agg ----
  agg_bucket_kernel<true><<<NB_BUCK, 512, 0, stream>>>(
      (const unsigned short*)hA, packed, bstart, b1, hB, N);

  // ---- Layer 2 ----
  mfma_gemm64<64, true, true><<<gemm_grid, 256, 0, stream>>>(hB, W2, hA, N);
  agg_bucket_kernel<true><<<NB_BUCK, 512, 0, stream>>>(
      (const unsigned short*)hA, packed, bstart, b2, hB, N);

  // ---- Layer 3 (fp32 out) ----
  mfma_gemm64<64, true, true><<<gemm_grid, 256, 0, stream>>>(hB, W3, hA, N);
  agg_bucket_kernel<false><<<NB_BUCK, 512, 0, stream>>>(
      (const unsigned short*)hA, packed, bstart, b3, out, N);
}

// Round 8
// 236.965 us; speedup vs baseline: 8.8660x; 8.8660x over previous
//
#include <hip/hip_runtime.h>

#define N_NODES_C 100000
#define N_EDGES_C 1600000
#define NPB 256                   // partition blocks
#define CH (N_EDGES_C / NPB)      // 6250 edges/partition block (exact)
#define BUCK_SH 7
#define BUCK_NODES 128
#define NB_BUCK 782               // ceil(100000 / 128)

typedef short short8 __attribute__((ext_vector_type(8)));
typedef float f32x4 __attribute__((ext_vector_type(4)));

// float -> bf16 bits (RNE)
__device__ __forceinline__ short f2bf(float f) {
  unsigned u = __builtin_bit_cast(unsigned, f);
  unsigned r = (u + 0x7FFFu + ((u >> 16) & 1u)) >> 16;
  return (short)r;
}
__device__ __forceinline__ float bf_lo(unsigned u) {
  return __builtin_bit_cast(float, u << 16);
}
__device__ __forceinline__ float bf_hi(unsigned u) {
  return __builtin_bit_cast(float, u & 0xFFFF0000u);
}

// ---------------------------------------------------------------------------
// MFMA GEMM body: out[n][64] = in[n][K] @ W[K][64]
// 4 waves/block, each wave a 16x64 tile via 4 n-tiles of mfma 16x16x32_bf16.
// ---------------------------------------------------------------------------
template <int K, bool IN_BF, bool OUT_BF>
__device__ __forceinline__ void gemm64_body(
    int gblock, const void* __restrict__ in_, const float* __restrict__ W,
    void* __restrict__ out_, int n_rows) {
  constexpr int KS = K / 32;
  int wave = threadIdx.x >> 6;
  int lane = threadIdx.x & 63;
  int row0 = (gblock * 4 + wave) * 16;
  if (row0 >= n_rows) return;  // n_rows % 16 == 0 -> full tiles only

  int lrow = lane & 15;
  int lk = (lane >> 4) * 8;

  short8 bfrag[KS][4];
#pragma unroll
  for (int ks = 0; ks < KS; ++ks)
#pragma unroll
    for (int nt = 0; nt < 4; ++nt) {
      short8 b;
#pragma unroll
      for (int j = 0; j < 8; ++j)
        b[j] = f2bf(W[(size_t)(ks * 32 + lk + j) * 64 + nt * 16 + lrow]);
      bfrag[ks][nt] = b;
    }

  int row = row0 + lrow;
  f32x4 acc[4] = {};
#pragma unroll
  for (int ks = 0; ks < KS; ++ks) {
    short8 a;
    if constexpr (IN_BF) {
      const short* ip = (const short*)in_ + (size_t)row * K + ks * 32 + lk;
      a = *(const short8*)ip;
    } else {
      const float* ip = (const float*)in_ + (size_t)row * K + ks * 32 + lk;
      f32x4 v0 = *(const f32x4*)(ip);
      f32x4 v1 = *(const f32x4*)(ip + 4);
#pragma unroll
      for (int j = 0; j < 4; ++j) {
        a[j] = f2bf(v0[j]);
        a[4 + j] = f2bf(v1[j]);
      }
    }
#pragma unroll
    for (int nt = 0; nt < 4; ++nt)
      acc[nt] = __builtin_amdgcn_mfma_f32_16x16x32_bf16(a, bfrag[ks][nt],
                                                        acc[nt], 0, 0, 0);
  }

  int crow = row0 + (lane >> 4) * 4;
#pragma unroll
  for (int nt = 0; nt < 4; ++nt) {
    int ocol = nt * 16 + lrow;
#pragma unroll
    for (int r = 0; r < 4; ++r) {
      if constexpr (OUT_BF)
        ((short*)out_)[(size_t)(crow + r) * 64 + ocol] = f2bf(acc[nt][r]);
      else
        ((float*)out_)[(size_t)(crow + r) * 64 + ocol] = acc[nt][r];
    }
  }
}

template <int K, bool IN_BF, bool OUT_BF>
__global__ __launch_bounds__(256) void mfma_gemm64(
    const void* __restrict__ in_, const float* __restrict__ W,
    void* __restrict__ out_, int n_rows) {
  gemm64_body<K, IN_BF, OUT_BF>(blockIdx.x, in_, W, out_, n_rows);
}

// ---------------------------------------------------------------------------
// Fused: blocks [0, gemm_blocks) = GEMM1 (x@W1 -> hA bf16).
// Blocks [gemm_blocks, +NPB) = bucket histogram of an edge chunk via LDS INT
// atomics (native ds_add, zero global atomics) -> countsT[bucket][blk].
// ---------------------------------------------------------------------------
__global__ __launch_bounds__(256) void hist_gemm1_kernel(
    const float* __restrict__ x, const float* __restrict__ W1,
    short* __restrict__ hA, int n_rows, int gemm_blocks,
    const int* __restrict__ dst, int* __restrict__ countsT) {
  __shared__ int lhist[NB_BUCK];
  int b = (int)blockIdx.x;
  if (b < gemm_blocks) {
    gemm64_body<128, false, true>(b, x, W1, hA, n_rows);
    return;
  }
  int cb = b - gemm_blocks;
  for (int i = threadIdx.x; i < NB_BUCK; i += 256) lhist[i] = 0;
  __syncthreads();
  int beg = cb * CH, end = beg + CH;
  for (int i = beg + (int)threadIdx.x; i < end; i += 256)
    atomicAdd(&lhist[((unsigned)dst[i]) >> BUCK_SH], 1);
  __syncthreads();
  for (int bb = threadIdx.x; bb < NB_BUCK; bb += 256)
    countsT[bb * NPB + cb] = lhist[bb];
}

// ---------------------------------------------------------------------------
// K1: per-bucket exclusive scan over NPB=256 per-block counts (in place)
// + bucket total. One wave per bucket; lane holds 4 values.
// ---------------------------------------------------------------------------
__global__ __launch_bounds__(256) void scan_buckets_kernel(
    int* __restrict__ countsT, int* __restrict__ btot) {
  int b = blockIdx.x * 4 + (threadIdx.x >> 6);
  int lane = threadIdx.x & 63;
  if (b >= NB_BUCK) return;
  int4 v = *(const int4*)(countsT + b * NPB + lane * 4);
  int s = v.x + v.y + v.z + v.w;
  int incl = s;
#pragma unroll
  for (int d = 1; d < 64; d <<= 1) {
    int t = __shfl_up(incl, d, 64);
    if (lane >= d) incl += t;
  }
  int excl = incl - s;
  int4 o;
  o.x = excl;
  o.y = excl + v.x;
  o.z = o.y + v.y;
  o.w = o.z + v.z;
  *(int4*)(countsT + b * NPB + lane * 4) = o;
  if (lane == 63) btot[b] = incl;
}

// K2: exclusive scan of the 782 bucket totals -> bstart[0..NB_BUCK].
__global__ __launch_bounds__(1024) void scan_btot_kernel(
    const int* __restrict__ btot, int* __restrict__ bstart) {
  __shared__ int lds[1024];
  int t = threadIdx.x;
  int v = (t < NB_BUCK) ? btot[t] : 0;
  lds[t] = v;
  __syncthreads();
  for (int off = 1; off < 1024; off <<= 1) {
    int tv = (t >= off) ? lds[t - off] : 0;
    __syncthreads();
    lds[t] += tv;
    __syncthreads();
  }
  if (t < NB_BUCK) bstart[t] = lds[t] - v;
  if (t == NB_BUCK - 1) bstart[NB_BUCK] = lds[t];
}

// ---------------------------------------------------------------------------
// Partition pass: scatter packed edge words ((ldst<<17)|src) into bucket
// order. LDS int cursors; writes land in per-(bucket,block) contiguous runs.
// ---------------------------------------------------------------------------
__global__ __launch_bounds__(256) void partition_kernel(
    const int* __restrict__ src, const int* __restrict__ dst,
    const int* __restrict__ offs /* countsT after K1 */,
    const int* __restrict__ bstart, unsigned* __restrict__ packed) {
  __shared__ int cur[NB_BUCK];
  int blk = (int)blockIdx.x;
  for (int bb = threadIdx.x; bb < NB_BUCK; bb += 256)
    cur[bb] = bstart[bb] + offs[bb * NPB + blk];
  __syncthreads();
  int beg = blk * CH, end = beg + CH;
  for (int i = beg + (int)threadIdx.x; i < end; i += 256) {
    int d = dst[i];
    int s = src[i];
    int bb = ((unsigned)d) >> BUCK_SH;
    int pos = atomicAdd(&cur[bb], 1);
    packed[pos] = ((unsigned)(d & (BUCK_NODES - 1)) << 17) | (unsigned)s;
  }
}

// ---------------------------------------------------------------------------
// Per-bucket counting sort: block = bucket; 128 local dst bins; native int
// LDS atomics. Emits dst-sorted col[] (src ids) + row_ptr[] (global CSR).
// ---------------------------------------------------------------------------
__global__ __launch_bounds__(256) void sort_bucket_kernel(
    const unsigned* __restrict__ packed, const int* __restrict__ bstart,
    int* __restrict__ col, int* __restrict__ row_ptr, int n_nodes,
    int n_edges) {
  __shared__ int lhist[BUCK_NODES];
  __shared__ int lcur[BUCK_NODES];
  __shared__ int wsum0;
  int b = (int)blockIdx.x;
  int beg = bstart[b], end = bstart[b + 1];
  int t = (int)threadIdx.x;

  if (t < BUCK_NODES) lhist[t] = 0;
  __syncthreads();
  for (int e = beg + t; e < end; e += 256)
    atomicAdd(&lhist[packed[e] >> 17], 1);
  __syncthreads();

  // exclusive scan of 128 counts across first two waves
  int v = 0, incl = 0;
  if (t < BUCK_NODES) {
    v = lhist[t];
    incl = v;
#pragma unroll
    for (int d = 1; d < 64; d <<= 1) {
      int u = __shfl_up(incl, d, 64);
      if ((t & 63) >= d) incl += u;
    }
  }
  if (t == 63) wsum0 = incl;
  __syncthreads();
  if (t >= 64 && t < BUCK_NODES) incl += wsum0;
  if (t < BUCK_NODES) {
    int excl = incl - v;
    lcur[t] = excl;
    int node = b * BUCK_NODES + t;
    if (node < n_nodes) row_ptr[node] = beg + excl;
  }
  if (b == NB_BUCK - 1 && t == 0) row_ptr[n_nodes] = n_edges;
  __syncthreads();

  for (int e = beg + t; e < end; e += 256) {
    unsigned pe = packed[e];
    int ld = (int)(pe >> 17);
    int pos = beg + atomicAdd(&lcur[ld], 1);
    col[pos] = (int)(pe & 0x1FFFFu);
  }
}

// ---------------------------------------------------------------------------
// Pull aggregation + bias + ReLU (round-6 proven). h bf16 [N][64]. Wave per
// node; lane = (edge-parity half) x (channel pair). 8 edges/iter.
// ---------------------------------------------------------------------------
template <bool OUT_BF>
__global__ __launch_bounds__(256) void agg64_kernel(
    const short* __restrict__ h, const int* __restrict__ row_ptr,
    const int* __restrict__ col, const float* __restrict__ bias,
    void* __restrict__ out, int n_nodes) {
  int node = blockIdx.x * 4 + (threadIdx.x >> 6);
  if (node >= n_nodes) return;
  int lane = threadIdx.x & 63;
  int half = lane >> 5;
  int cp = lane & 31;

  int beg = row_ptr[node];
  int end = row_ptr[node + 1];
  float a0 = 0.f, a1 = 0.f, b0 = 0.f, b1 = 0.f;
  int e = beg + half;
  for (; e + 6 < end; e += 8) {
    int s0 = col[e];
    int s1 = col[e + 2];
    int s2 = col[e + 4];
    int s3 = col[e + 6];
    unsigned u0 = *(const unsigned*)(h + (size_t)s0 * 64 + cp * 2);
    unsigned u1 = *(const unsigned*)(h + (size_t)s1 * 64 + cp * 2);
    unsigned u2 = *(const unsigned*)(h + (size_t)s2 * 64 + cp * 2);
    unsigned u3 = *(const unsigned*)(h + (size_t)s3 * 64 + cp * 2);
    a0 += bf_lo(u0) + bf_lo(u1);
    a1 += bf_hi(u0) + bf_hi(u1);
    b0 += bf_lo(u2) + bf_lo(u3);
    b1 += bf_hi(u2) + bf_hi(u3);
  }
  for (; e < end; e += 2) {
    int s = col[e];
    unsigned u = *(const unsigned*)(h + (size_t)s * 64 + cp * 2);
    a0 += bf_lo(u);
    a1 += bf_hi(u);
  }
  a0 += b0;
  a1 += b1;
  a0 += __shfl_xor(a0, 32);
  a1 += __shfl_xor(a1, 32);

  float r0 = fmaxf(a0 + bias[cp * 2 + 0], 0.f);
  float r1 = fmaxf(a1 + bias[cp * 2 + 1], 0.f);
  if (lane < 32) {
    if constexpr (OUT_BF) {
      unsigned pack = (unsigned)(unsigned short)f2bf(r0) |
                      ((unsigned)(unsigned short)f2bf(r1) << 16);
      ((unsigned*)out)[(size_t)node * 32 + cp] = pack;
    } else {
      float2 v;
      v.x = r0;
      v.y = r1;
      ((float2*)out)[(size_t)node * 32 + cp] = v;
    }
  }
}

extern "C" void kernel_launch(void* const* d_in, const int* in_sizes, int n_in,
                              void* d_out, int out_size, void* d_ws,
                              size_t ws_size, hipStream_t stream) {
  const float* x = (const float*)d_in[0];
  const int* src = (const int*)d_in[1];
  const int* dst = (const int*)d_in[2];
  const float* W1 = (const float*)d_in[3];
  const float* b1 = (const float*)d_in[4];
  const float* W2 = (const float*)d_in[5];
  const float* b2 = (const float*)d_in[6];
  const float* W3 = (const float*)d_in[7];
  const float* b3 = (const float*)d_in[8];
  float* out = (float*)d_out;

  const int N = N_NODES_C;
  const int E = N_EDGES_C;

  // Workspace layout (43 MB):
  //   [0, 1MB)     countsT[NB_BUCK][NPB] (800 KB; becomes offs after K1)
  //   [1MB, +4KB)  btot ; [1MB+16KB) bstart
  //   [2, 3MB)     row_ptr (N+1)
  //   [3, 10MB)    packed edges (E u32)
  //   [10, 17MB)   col (E int, dst-sorted src)
  //   [17, 30MB)   hA ; [30, 43MB) hB
  char* ws = (char*)d_ws;
  int* countsT = (int*)(ws + 0);
  int* btot = (int*)(ws + (1u << 20));
  int* bstart = (int*)(ws + (1u << 20) + (16u << 10));
  int* row_ptr = (int*)(ws + (2u << 20));
  unsigned* packed = (unsigned*)(ws + (3u << 20));
  int* col = (int*)(ws + (10u << 20));
  short* hA = (short*)(ws + (17u << 20));
  short* hB = (short*)(ws + (30u << 20));

  const int gemm_grid = (N + 63) / 64;  // 1563
  const int k1_grid = (NB_BUCK + 3) / 4;
  const int agg_grid = (N + 3) / 4;

  // ---- GEMM1 ∥ bucket histogram; then scan -> partition -> counting sort ----
  hist_gemm1_kernel<<<gemm_grid + NPB, 256, 0, stream>>>(x, W1, hA, N,
                                                         gemm_grid, dst,
                                                         countsT);
  scan_buckets_kernel<<<k1_grid, 256, 0, stream>>>(countsT, btot);
  scan_btot_kernel<<<1, 1024, 0, stream>>>(btot, bstart);
  partition_kernel<<<NPB, 256, 0, stream>>>(src, dst, countsT, bstart, packed);
  sort_bucket_kernel<<<NB_BUCK, 256, 0, stream>>>(packed, bstart, col, row_ptr,
                                                  N, E);

  // ---- Layer 1 agg ----
  agg64_kernel<true><<<agg_grid, 256, 0, stream>>>(hA, row_ptr, col, b1, hB, N);

  // ---- Layer 2 ----
  mfma_gemm64<64, true, true><<<gemm_grid, 256, 0, stream>>>(hB, W2, hA, N);
  agg64_kernel<true><<<agg_grid, 256, 0, stream>>>(hA, row_ptr, col, b2, hB, N);

  // ---- Layer 3 (fp32 out) ----
  mfma_gemm64<64, true, true><<<gemm_grid, 256, 0, stream>>>(hB, W3, hA, N);
  agg64_kernel<false><<<agg_grid, 256, 0, stream>>>(hA, row_ptr, col, b3, out, N);
}

// Round 9
// 228.815 us; speedup vs baseline: 9.1817x; 1.0356x over previous
//
#include <hip/hip_runtime.h>

#define N_NODES_C 100000
#define N_EDGES_C 1600000
#define NPB 256                   // partition blocks
#define CH (N_EDGES_C / NPB)      // 6250 edges/partition block (exact)
#define BUCK_SH 7
#define BUCK_NODES 128
#define NB_BUCK 782               // ceil(100000 / 128)

typedef short short8 __attribute__((ext_vector_type(8)));
typedef float f32x4 __attribute__((ext_vector_type(4)));

// float -> bf16 bits (RNE)
__device__ __forceinline__ short f2bf(float f) {
  unsigned u = __builtin_bit_cast(unsigned, f);
  unsigned r = (u + 0x7FFFu + ((u >> 16) & 1u)) >> 16;
  return (short)r;
}
__device__ __forceinline__ float bf_lo(unsigned u) {
  return __builtin_bit_cast(float, u << 16);
}
__device__ __forceinline__ float bf_hi(unsigned u) {
  return __builtin_bit_cast(float, u & 0xFFFF0000u);
}

// ---------------------------------------------------------------------------
// MFMA GEMM body: out[n][64] = in[n][K] @ W[K][64]
// 4 waves/block, each wave a 16x64 tile via 4 n-tiles of mfma 16x16x32_bf16.
// ---------------------------------------------------------------------------
template <int K, bool IN_BF, bool OUT_BF>
__device__ __forceinline__ void gemm64_body(
    int gblock, const void* __restrict__ in_, const float* __restrict__ W,
    void* __restrict__ out_, int n_rows) {
  constexpr int KS = K / 32;
  int wave = threadIdx.x >> 6;
  int lane = threadIdx.x & 63;
  int row0 = (gblock * 4 + wave) * 16;
  if (row0 >= n_rows) return;  // n_rows % 16 == 0 -> full tiles only

  int lrow = lane & 15;
  int lk = (lane >> 4) * 8;

  short8 bfrag[KS][4];
#pragma unroll
  for (int ks = 0; ks < KS; ++ks)
#pragma unroll
    for (int nt = 0; nt < 4; ++nt) {
      short8 b;
#pragma unroll
      for (int j = 0; j < 8; ++j)
        b[j] = f2bf(W[(size_t)(ks * 32 + lk + j) * 64 + nt * 16 + lrow]);
      bfrag[ks][nt] = b;
    }

  int row = row0 + lrow;
  f32x4 acc[4] = {};
#pragma unroll
  for (int ks = 0; ks < KS; ++ks) {
    short8 a;
    if constexpr (IN_BF) {
      const short* ip = (const short*)in_ + (size_t)row * K + ks * 32 + lk;
      a = *(const short8*)ip;
    } else {
      const float* ip = (const float*)in_ + (size_t)row * K + ks * 32 + lk;
      f32x4 v0 = *(const f32x4*)(ip);
      f32x4 v1 = *(const f32x4*)(ip + 4);
#pragma unroll
      for (int j = 0; j < 4; ++j) {
        a[j] = f2bf(v0[j]);
        a[4 + j] = f2bf(v1[j]);
      }
    }
#pragma unroll
    for (int nt = 0; nt < 4; ++nt)
      acc[nt] = __builtin_amdgcn_mfma_f32_16x16x32_bf16(a, bfrag[ks][nt],
                                                        acc[nt], 0, 0, 0);
  }

  int crow = row0 + (lane >> 4) * 4;
#pragma unroll
  for (int nt = 0; nt < 4; ++nt) {
    int ocol = nt * 16 + lrow;
#pragma unroll
    for (int r = 0; r < 4; ++r) {
      if constexpr (OUT_BF)
        ((short*)out_)[(size_t)(crow + r) * 64 + ocol] = f2bf(acc[nt][r]);
      else
        ((float*)out_)[(size_t)(crow + r) * 64 + ocol] = acc[nt][r];
    }
  }
}

template <int K, bool IN_BF, bool OUT_BF>
__global__ __launch_bounds__(256) void mfma_gemm64(
    const void* __restrict__ in_, const float* __restrict__ W,
    void* __restrict__ out_, int n_rows) {
  gemm64_body<K, IN_BF, OUT_BF>(blockIdx.x, in_, W, out_, n_rows);
}

// ---------------------------------------------------------------------------
// Fused: blocks [0, gemm_blocks) = GEMM1 (x@W1 -> hA bf16).
// Blocks [gemm_blocks, +NPB) = bucket histogram of an edge chunk via LDS INT
// atomics (native ds_add, zero global atomics) -> countsT[bucket][blk].
// ---------------------------------------------------------------------------
__global__ __launch_bounds__(256) void hist_gemm1_kernel(
    const float* __restrict__ x, const float* __restrict__ W1,
    short* __restrict__ hA, int n_rows, int gemm_blocks,
    const int* __restrict__ dst, int* __restrict__ countsT) {
  __shared__ int lhist[NB_BUCK];
  int b = (int)blockIdx.x;
  if (b < gemm_blocks) {
    gemm64_body<128, false, true>(b, x, W1, hA, n_rows);
    return;
  }
  int cb = b - gemm_blocks;
  for (int i = threadIdx.x; i < NB_BUCK; i += 256) lhist[i] = 0;
  __syncthreads();
  int beg = cb * CH, end = beg + CH;
  for (int i = beg + (int)threadIdx.x; i < end; i += 256)
    atomicAdd(&lhist[((unsigned)dst[i]) >> BUCK_SH], 1);
  __syncthreads();
  for (int bb = threadIdx.x; bb < NB_BUCK; bb += 256)
    countsT[bb * NPB + cb] = lhist[bb];
}

// ---------------------------------------------------------------------------
// K1: per-bucket exclusive scan over NPB=256 per-block counts (in place)
// + bucket total. One wave per bucket; lane holds 4 values.
// ---------------------------------------------------------------------------
__global__ __launch_bounds__(256) void scan_buckets_kernel(
    int* __restrict__ countsT, int* __restrict__ btot) {
  int b = blockIdx.x * 4 + (threadIdx.x >> 6);
  int lane = threadIdx.x & 63;
  if (b >= NB_BUCK) return;
  int4 v = *(const int4*)(countsT + b * NPB + lane * 4);
  int s = v.x + v.y + v.z + v.w;
  int incl = s;
#pragma unroll
  for (int d = 1; d < 64; d <<= 1) {
    int t = __shfl_up(incl, d, 64);
    if (lane >= d) incl += t;
  }
  int excl = incl - s;
  int4 o;
  o.x = excl;
  o.y = excl + v.x;
  o.z = o.y + v.y;
  o.w = o.z + v.z;
  *(int4*)(countsT + b * NPB + lane * 4) = o;
  if (lane == 63) btot[b] = incl;
}

// K2: exclusive scan of the 782 bucket totals -> bstart[0..NB_BUCK].
__global__ __launch_bounds__(1024) void scan_btot_kernel(
    const int* __restrict__ btot, int* __restrict__ bstart) {
  __shared__ int lds[1024];
  int t = threadIdx.x;
  int v = (t < NB_BUCK) ? btot[t] : 0;
  lds[t] = v;
  __syncthreads();
  for (int off = 1; off < 1024; off <<= 1) {
    int tv = (t >= off) ? lds[t - off] : 0;
    __syncthreads();
    lds[t] += tv;
    __syncthreads();
  }
  if (t < NB_BUCK) bstart[t] = lds[t] - v;
  if (t == NB_BUCK - 1) bstart[NB_BUCK] = lds[t];
}

// ---------------------------------------------------------------------------
// Partition pass: scatter packed edge words ((ldst<<17)|src) into bucket
// order. LDS int cursors; writes land in per-(bucket,block) contiguous runs.
// ---------------------------------------------------------------------------
__global__ __launch_bounds__(256) void partition_kernel(
    const int* __restrict__ src, const int* __restrict__ dst,
    const int* __restrict__ offs /* countsT after K1 */,
    const int* __restrict__ bstart, unsigned* __restrict__ packed) {
  __shared__ int cur[NB_BUCK];
  int blk = (int)blockIdx.x;
  for (int bb = threadIdx.x; bb < NB_BUCK; bb += 256)
    cur[bb] = bstart[bb] + offs[bb * NPB + blk];
  __syncthreads();
  int beg = blk * CH, end = beg + CH;
  for (int i = beg + (int)threadIdx.x; i < end; i += 256) {
    int d = dst[i];
    int s = src[i];
    int bb = ((unsigned)d) >> BUCK_SH;
    int pos = atomicAdd(&cur[bb], 1);
    packed[pos] = ((unsigned)(d & (BUCK_NODES - 1)) << 17) | (unsigned)s;
  }
}

// ---------------------------------------------------------------------------
// Per-bucket counting sort: block = bucket; 128 local dst bins; native int
// LDS atomics. Emits dst-sorted col[] (src ids) + row_ptr[] (global CSR).
// ---------------------------------------------------------------------------
__global__ __launch_bounds__(256) void sort_bucket_kernel(
    const unsigned* __restrict__ packed, const int* __restrict__ bstart,
    int* __restrict__ col, int* __restrict__ row_ptr, int n_nodes,
    int n_edges) {
  __shared__ int lhist[BUCK_NODES];
  __shared__ int lcur[BUCK_NODES];
  __shared__ int wsum0;
  int b = (int)blockIdx.x;
  int beg = bstart[b], end = bstart[b + 1];
  int t = (int)threadIdx.x;

  if (t < BUCK_NODES) lhist[t] = 0;
  __syncthreads();
  for (int e = beg + t; e < end; e += 256)
    atomicAdd(&lhist[packed[e] >> 17], 1);
  __syncthreads();

  int v = 0, incl = 0;
  if (t < BUCK_NODES) {
    v = lhist[t];
    incl = v;
#pragma unroll
    for (int d = 1; d < 64; d <<= 1) {
      int u = __shfl_up(incl, d, 64);
      if ((t & 63) >= d) incl += u;
    }
  }
  if (t == 63) wsum0 = incl;
  __syncthreads();
  if (t >= 64 && t < BUCK_NODES) incl += wsum0;
  if (t < BUCK_NODES) {
    int excl = incl - v;
    lcur[t] = excl;
    int node = b * BUCK_NODES + t;
    if (node < n_nodes) row_ptr[node] = beg + excl;
  }
  if (b == NB_BUCK - 1 && t == 0) row_ptr[n_nodes] = n_edges;
  __syncthreads();

  for (int e = beg + t; e < end; e += 256) {
    unsigned pe = packed[e];
    int ld = (int)(pe >> 17);
    int pos = beg + atomicAdd(&lcur[ld], 1);
    col[pos] = (int)(pe & 0x1FFFFu);
  }
}

// ---------------------------------------------------------------------------
// Pull aggregation + bias + ReLU. h bf16 [N][64]. Wave per node; lane =
// (edge slot 0..3) x (channel quad 0..15). Each lane loads uint2 (8B = 4 ch);
// main loop = 16 edges/iter -> 4 independent 8B gathers in flight per lane.
// Combine slots via shfl_xor(16)+shfl_xor(32); lanes 0..15 store the node row.
// ---------------------------------------------------------------------------
template <bool OUT_BF>
__global__ __launch_bounds__(256) void agg64_kernel(
    const short* __restrict__ h, const int* __restrict__ row_ptr,
    const int* __restrict__ col, const float* __restrict__ bias,
    void* __restrict__ out, int n_nodes) {
  int node = blockIdx.x * 4 + (threadIdx.x >> 6);
  if (node >= n_nodes) return;
  int lane = threadIdx.x & 63;
  int slot = lane >> 4;  // 4 edge slots
  int q = lane & 15;     // channel quad: ch 4q..4q+3

  int beg = row_ptr[node];
  int end = row_ptr[node + 1];
  float s0 = 0.f, s1 = 0.f, s2 = 0.f, s3 = 0.f;
  float t0 = 0.f, t1 = 0.f, t2 = 0.f, t3 = 0.f;
  int e = beg + slot;
  // 16 edges/iter: 4 per slot, 4 gathers in flight per lane
  for (; e + 12 < end; e += 16) {
    int sa = col[e];
    int sb = col[e + 4];
    int sc = col[e + 8];
    int sd = col[e + 12];
    uint2 ua = *(const uint2*)(h + (size_t)sa * 64 + q * 4);
    uint2 ub = *(const uint2*)(h + (size_t)sb * 64 + q * 4);
    uint2 uc = *(const uint2*)(h + (size_t)sc * 64 + q * 4);
    uint2 ud = *(const uint2*)(h + (size_t)sd * 64 + q * 4);
    s0 += bf_lo(ua.x) + bf_lo(ub.x);
    s1 += bf_hi(ua.x) + bf_hi(ub.x);
    s2 += bf_lo(ua.y) + bf_lo(ub.y);
    s3 += bf_hi(ua.y) + bf_hi(ub.y);
    t0 += bf_lo(uc.x) + bf_lo(ud.x);
    t1 += bf_hi(uc.x) + bf_hi(ud.x);
    t2 += bf_lo(uc.y) + bf_lo(ud.y);
    t3 += bf_hi(uc.y) + bf_hi(ud.y);
  }
  for (; e < end; e += 4) {
    int sa = col[e];
    uint2 ua = *(const uint2*)(h + (size_t)sa * 64 + q * 4);
    s0 += bf_lo(ua.x);
    s1 += bf_hi(ua.x);
    s2 += bf_lo(ua.y);
    s3 += bf_hi(ua.y);
  }
  s0 += t0;
  s1 += t1;
  s2 += t2;
  s3 += t3;
  s0 += __shfl_xor(s0, 16);
  s1 += __shfl_xor(s1, 16);
  s2 += __shfl_xor(s2, 16);
  s3 += __shfl_xor(s3, 16);
  s0 += __shfl_xor(s0, 32);
  s1 += __shfl_xor(s1, 32);
  s2 += __shfl_xor(s2, 32);
  s3 += __shfl_xor(s3, 32);

  if (lane < 16) {
    float r0 = fmaxf(s0 + bias[q * 4 + 0], 0.f);
    float r1 = fmaxf(s1 + bias[q * 4 + 1], 0.f);
    float r2 = fmaxf(s2 + bias[q * 4 + 2], 0.f);
    float r3 = fmaxf(s3 + bias[q * 4 + 3], 0.f);
    if constexpr (OUT_BF) {
      uint2 p;
      p.x = (unsigned)(unsigned short)f2bf(r0) |
            ((unsigned)(unsigned short)f2bf(r1) << 16);
      p.y = (unsigned)(unsigned short)f2bf(r2) |
            ((unsigned)(unsigned short)f2bf(r3) << 16);
      ((uint2*)out)[(size_t)node * 16 + q] = p;
    } else {
      float4 v;
      v.x = r0;
      v.y = r1;
      v.z = r2;
      v.w = r3;
      ((float4*)out)[(size_t)node * 16 + q] = v;
    }
  }
}

extern "C" void kernel_launch(void* const* d_in, const int* in_sizes, int n_in,
                              void* d_out, int out_size, void* d_ws,
                              size_t ws_size, hipStream_t stream) {
  const float* x = (const float*)d_in[0];
  const int* src = (const int*)d_in[1];
  const int* dst = (const int*)d_in[2];
  const float* W1 = (const float*)d_in[3];
  const float* b1 = (const float*)d_in[4];
  const float* W2 = (const float*)d_in[5];
  const float* b2 = (const float*)d_in[6];
  const float* W3 = (const float*)d_in[7];
  const float* b3 = (const float*)d_in[8];
  float* out = (float*)d_out;

  const int N = N_NODES_C;
  const int E = N_EDGES_C;

  // Workspace layout (43 MB):
  //   [0, 1MB)     countsT[NB_BUCK][NPB] (800 KB; becomes offs after K1)
  //   [1MB, +4KB)  btot ; [1MB+16KB) bstart
  //   [2, 3MB)     row_ptr (N+1)
  //   [3, 10MB)    packed edges (E u32)
  //   [10, 17MB)   col (E int, dst-sorted src)
  //   [17, 30MB)   hA ; [30, 43MB) hB
  char* ws = (char*)d_ws;
  int* countsT = (int*)(ws + 0);
  int* btot = (int*)(ws + (1u << 20));
  int* bstart = (int*)(ws + (1u << 20) + (16u << 10));
  int* row_ptr = (int*)(ws + (2u << 20));
  unsigned* packed = (unsigned*)(ws + (3u << 20));
  int* col = (int*)(ws + (10u << 20));
  short* hA = (short*)(ws + (17u << 20));
  short* hB = (short*)(ws + (30u << 20));

  const int gemm_grid = (N + 63) / 64;  // 1563
  const int k1_grid = (NB_BUCK + 3) / 4;
  const int agg_grid = (N + 3) / 4;

  // ---- GEMM1 ∥ bucket histogram; then scan -> partition -> counting sort ----
  hist_gemm1_kernel<<<gemm_grid + NPB, 256, 0, stream>>>(x, W1, hA, N,
                                                         gemm_grid, dst,
                                                         countsT);
  scan_buckets_kernel<<<k1_grid, 256, 0, stream>>>(countsT, btot);
  scan_btot_kernel<<<1, 1024, 0, stream>>>(btot, bstart);
  partition_kernel<<<NPB, 256, 0, stream>>>(src, dst, countsT, bstart, packed);
  sort_bucket_kernel<<<NB_BUCK, 256, 0, stream>>>(packed, bstart, col, row_ptr,
                                                  N, E);

  // ---- Layer 1 agg ----
  agg64_kernel<true><<<agg_grid, 256, 0, stream>>>(hA, row_ptr, col, b1, hB, N);

  // ---- Layer 2 ----
  mfma_gemm64<64, true, true><<<gemm_grid, 256, 0, stream>>>(hB, W2, hA, N);
  agg64_kernel<true><<<agg_grid, 256, 0, stream>>>(hA, row_ptr, col, b2, hB, N);

  // ---- Layer 3 (fp32 out) ----
  mfma_gemm64<64, true, true><<<gemm_grid, 256, 0, stream>>>(hB, W3, hA, N);
  agg64_kernel<false><<<agg_grid, 256, 0, stream>>>(hA, row_ptr, col, b3, out, N);
}

// Round 10
// 213.422 us; speedup vs baseline: 9.8440x; 1.0721x over previous
//
#include <hip/hip_runtime.h>

#define N_NODES_C 100000
#define N_EDGES_C 1600000
#define NPB 256                   // partition blocks
#define CH (N_EDGES_C / NPB)      // 6250 edges/partition block (exact)
#define BUCK_SH 7
#define BUCK_NODES 128
#define NB_BUCK 782               // ceil(100000 / 128)

typedef short short8 __attribute__((ext_vector_type(8)));
typedef float f32x4 __attribute__((ext_vector_type(4)));

// float -> bf16 bits (RNE)
__device__ __forceinline__ short f2bf(float f) {
  unsigned u = __builtin_bit_cast(unsigned, f);
  unsigned r = (u + 0x7FFFu + ((u >> 16) & 1u)) >> 16;
  return (short)r;
}
__device__ __forceinline__ float bf_lo(unsigned u) {
  return __builtin_bit_cast(float, u << 16);
}
__device__ __forceinline__ float bf_hi(unsigned u) {
  return __builtin_bit_cast(float, u & 0xFFFF0000u);
}

// ---------------------------------------------------------------------------
// MFMA GEMM body: out[n][64] = in[n][K] @ W[K][64] (layer-1 only now)
// ---------------------------------------------------------------------------
template <int K, bool IN_BF, bool OUT_BF>
__device__ __forceinline__ void gemm64_body(
    int gblock, const void* __restrict__ in_, const float* __restrict__ W,
    void* __restrict__ out_, int n_rows) {
  constexpr int KS = K / 32;
  int wave = threadIdx.x >> 6;
  int lane = threadIdx.x & 63;
  int row0 = (gblock * 4 + wave) * 16;
  if (row0 >= n_rows) return;

  int lrow = lane & 15;
  int lk = (lane >> 4) * 8;

  short8 bfrag[KS][4];
#pragma unroll
  for (int ks = 0; ks < KS; ++ks)
#pragma unroll
    for (int nt = 0; nt < 4; ++nt) {
      short8 b;
#pragma unroll
      for (int j = 0; j < 8; ++j)
        b[j] = f2bf(W[(size_t)(ks * 32 + lk + j) * 64 + nt * 16 + lrow]);
      bfrag[ks][nt] = b;
    }

  int row = row0 + lrow;
  f32x4 acc[4] = {};
#pragma unroll
  for (int ks = 0; ks < KS; ++ks) {
    short8 a;
    if constexpr (IN_BF) {
      const short* ip = (const short*)in_ + (size_t)row * K + ks * 32 + lk;
      a = *(const short8*)ip;
    } else {
      const float* ip = (const float*)in_ + (size_t)row * K + ks * 32 + lk;
      f32x4 v0 = *(const f32x4*)(ip);
      f32x4 v1 = *(const f32x4*)(ip + 4);
#pragma unroll
      for (int j = 0; j < 4; ++j) {
        a[j] = f2bf(v0[j]);
        a[4 + j] = f2bf(v1[j]);
      }
    }
#pragma unroll
    for (int nt = 0; nt < 4; ++nt)
      acc[nt] = __builtin_amdgcn_mfma_f32_16x16x32_bf16(a, bfrag[ks][nt],
                                                        acc[nt], 0, 0, 0);
  }

  int crow = row0 + (lane >> 4) * 4;
#pragma unroll
  for (int nt = 0; nt < 4; ++nt) {
    int ocol = nt * 16 + lrow;
#pragma unroll
    for (int r = 0; r < 4; ++r) {
      if constexpr (OUT_BF)
        ((short*)out_)[(size_t)(crow + r) * 64 + ocol] = f2bf(acc[nt][r]);
      else
        ((float*)out_)[(size_t)(crow + r) * 64 + ocol] = acc[nt][r];
    }
  }
}

// ---------------------------------------------------------------------------
// Standalone bucket histogram (LDS int atomics) -> countsT[bucket][blk]
// ---------------------------------------------------------------------------
__global__ __launch_bounds__(256) void hist_kernel(
    const int* __restrict__ dst, int* __restrict__ countsT) {
  __shared__ int lhist[NB_BUCK];
  int cb = (int)blockIdx.x;
  for (int i = threadIdx.x; i < NB_BUCK; i += 256) lhist[i] = 0;
  __syncthreads();
  int beg = cb * CH, end = beg + CH;
  for (int i = beg + (int)threadIdx.x; i < end; i += 256)
    atomicAdd(&lhist[((unsigned)dst[i]) >> BUCK_SH], 1);
  __syncthreads();
  for (int bb = threadIdx.x; bb < NB_BUCK; bb += 256)
    countsT[bb * NPB + cb] = lhist[bb];
}

// K1: per-bucket exclusive scan over NPB per-block counts (+ total).
__global__ __launch_bounds__(256) void scan_buckets_kernel(
    int* __restrict__ countsT, int* __restrict__ btot) {
  int b = blockIdx.x * 4 + (threadIdx.x >> 6);
  int lane = threadIdx.x & 63;
  if (b >= NB_BUCK) return;
  int4 v = *(const int4*)(countsT + b * NPB + lane * 4);
  int s = v.x + v.y + v.z + v.w;
  int incl = s;
#pragma unroll
  for (int d = 1; d < 64; d <<= 1) {
    int t = __shfl_up(incl, d, 64);
    if (lane >= d) incl += t;
  }
  int excl = incl - s;
  int4 o;
  o.x = excl;
  o.y = excl + v.x;
  o.z = o.y + v.y;
  o.w = o.z + v.z;
  *(int4*)(countsT + b * NPB + lane * 4) = o;
  if (lane == 63) btot[b] = incl;
}

// K2: exclusive scan of bucket totals -> bstart[0..NB_BUCK].
__global__ __launch_bounds__(1024) void scan_btot_kernel(
    const int* __restrict__ btot, int* __restrict__ bstart) {
  __shared__ int lds[1024];
  int t = threadIdx.x;
  int v = (t < NB_BUCK) ? btot[t] : 0;
  lds[t] = v;
  __syncthreads();
  for (int off = 1; off < 1024; off <<= 1) {
    int tv = (t >= off) ? lds[t - off] : 0;
    __syncthreads();
    lds[t] += tv;
    __syncthreads();
  }
  if (t < NB_BUCK) bstart[t] = lds[t] - v;
  if (t == NB_BUCK - 1) bstart[NB_BUCK] = lds[t];
}

// ---------------------------------------------------------------------------
// Fused: blocks [0,NPB) = partition (bucket scatter of packed edges);
// blocks [NPB, NPB+gemm_blocks) = GEMM1 (x@W1 -> hA bf16). Independent.
// ---------------------------------------------------------------------------
__global__ __launch_bounds__(256) void part_gemm1_kernel(
    const int* __restrict__ src, const int* __restrict__ dst,
    const int* __restrict__ offs /* countsT after K1 */,
    const int* __restrict__ bstart, unsigned* __restrict__ packed,
    const float* __restrict__ x, const float* __restrict__ W1,
    short* __restrict__ hA, int n_rows) {
  __shared__ int cur[NB_BUCK];
  int b = (int)blockIdx.x;
  if (b >= NPB) {
    gemm64_body<128, false, true>(b - NPB, x, W1, hA, n_rows);
    return;
  }
  for (int bb = threadIdx.x; bb < NB_BUCK; bb += 256)
    cur[bb] = bstart[bb] + offs[bb * NPB + b];
  __syncthreads();
  int beg = b * CH, end = beg + CH;
  for (int i = beg + (int)threadIdx.x; i < end; i += 256) {
    int d = dst[i];
    int s = src[i];
    int bb = ((unsigned)d) >> BUCK_SH;
    int pos = atomicAdd(&cur[bb], 1);
    packed[pos] = ((unsigned)(d & (BUCK_NODES - 1)) << 17) | (unsigned)s;
  }
}

// ---------------------------------------------------------------------------
// Per-bucket counting sort -> dst-sorted col[] + row_ptr[] (global CSR).
// ---------------------------------------------------------------------------
__global__ __launch_bounds__(256) void sort_bucket_kernel(
    const unsigned* __restrict__ packed, const int* __restrict__ bstart,
    int* __restrict__ col, int* __restrict__ row_ptr, int n_nodes,
    int n_edges) {
  __shared__ int lhist[BUCK_NODES];
  __shared__ int lcur[BUCK_NODES];
  __shared__ int wsum0;
  int b = (int)blockIdx.x;
  int beg = bstart[b], end = bstart[b + 1];
  int t = (int)threadIdx.x;

  if (t < BUCK_NODES) lhist[t] = 0;
  __syncthreads();
  for (int e = beg + t; e < end; e += 256)
    atomicAdd(&lhist[packed[e] >> 17], 1);
  __syncthreads();

  int v = 0, incl = 0;
  if (t < BUCK_NODES) {
    v = lhist[t];
    incl = v;
#pragma unroll
    for (int d = 1; d < 64; d <<= 1) {
      int u = __shfl_up(incl, d, 64);
      if ((t & 63) >= d) incl += u;
    }
  }
  if (t == 63) wsum0 = incl;
  __syncthreads();
  if (t >= 64 && t < BUCK_NODES) incl += wsum0;
  if (t < BUCK_NODES) {
    int excl = incl - v;
    lcur[t] = excl;
    int node = b * BUCK_NODES + t;
    if (node < n_nodes) row_ptr[node] = beg + excl;
  }
  if (b == NB_BUCK - 1 && t == 0) row_ptr[n_nodes] = n_edges;
  __syncthreads();

  for (int e = beg + t; e < end; e += 256) {
    unsigned pe = packed[e];
    int ld = (int)(pe >> 17);
    int pos = beg + atomicAdd(&lcur[ld], 1);
    col[pos] = (int)(pe & 0x1FFFFu);
  }
}

// ---------------------------------------------------------------------------
// Agg inner: aggregate one node's sorted edge range; returns s0..s3 for the
// channel quad q (all 64 lanes hold the result after the two shuffles).
// ---------------------------------------------------------------------------
__device__ __forceinline__ void agg_node(
    const short* __restrict__ h, const int* __restrict__ col, int beg, int end,
    int slot, int q, float& s0, float& s1, float& s2, float& s3) {
  s0 = s1 = s2 = s3 = 0.f;
  float t0 = 0.f, t1 = 0.f, t2 = 0.f, t3 = 0.f;
  int e = beg + slot;
  for (; e + 12 < end; e += 16) {
    int sa = col[e];
    int sb = col[e + 4];
    int sc = col[e + 8];
    int sd = col[e + 12];
    uint2 ua = *(const uint2*)(h + (size_t)sa * 64 + q * 4);
    uint2 ub = *(const uint2*)(h + (size_t)sb * 64 + q * 4);
    uint2 uc = *(const uint2*)(h + (size_t)sc * 64 + q * 4);
    uint2 ud = *(const uint2*)(h + (size_t)sd * 64 + q * 4);
    s0 += bf_lo(ua.x) + bf_lo(ub.x);
    s1 += bf_hi(ua.x) + bf_hi(ub.x);
    s2 += bf_lo(ua.y) + bf_lo(ub.y);
    s3 += bf_hi(ua.y) + bf_hi(ub.y);
    t0 += bf_lo(uc.x) + bf_lo(ud.x);
    t1 += bf_hi(uc.x) + bf_hi(ud.x);
    t2 += bf_lo(uc.y) + bf_lo(ud.y);
    t3 += bf_hi(uc.y) + bf_hi(ud.y);
  }
  for (; e < end; e += 4) {
    int sa = col[e];
    uint2 ua = *(const uint2*)(h + (size_t)sa * 64 + q * 4);
    s0 += bf_lo(ua.x);
    s1 += bf_hi(ua.x);
    s2 += bf_lo(ua.y);
    s3 += bf_hi(ua.y);
  }
  s0 += t0;
  s1 += t1;
  s2 += t2;
  s3 += t3;
  s0 += __shfl_xor(s0, 16);
  s1 += __shfl_xor(s1, 16);
  s2 += __shfl_xor(s2, 16);
  s3 += __shfl_xor(s3, 16);
  s0 += __shfl_xor(s0, 32);
  s1 += __shfl_xor(s1, 32);
  s2 += __shfl_xor(s2, 32);
  s3 += __shfl_xor(s3, 32);
}

// ---------------------------------------------------------------------------
// Fused agg + bias + ReLU + (row @ W) -> bf16. Block = 16 nodes, 4 waves;
// each wave aggregates 4 nodes into LDS rowbuf (f32, padded), then the block
// computes rowbuf[16][64] @ W via 1 MFMA n-tile per wave (2 k-steps).
// ---------------------------------------------------------------------------
__global__ __launch_bounds__(256) void agg_gemm_kernel(
    const short* __restrict__ h, const int* __restrict__ row_ptr,
    const int* __restrict__ col, const float* __restrict__ bias,
    const float* __restrict__ W, short* __restrict__ outg, int n_nodes) {
  __shared__ float rowbuf[16][68];  // 68-pad: phase-2 reads 2-way banked
  int wid = threadIdx.x >> 6;
  int lane = threadIdx.x & 63;
  int slot = lane >> 4;
  int q = lane & 15;
  int nbase = blockIdx.x * 16;

#pragma unroll
  for (int n = 0; n < 4; ++n) {
    int ln = wid * 4 + n;
    int node = nbase + ln;
    float s0, s1, s2, s3;
    agg_node(h, col, row_ptr[node], row_ptr[node + 1], slot, q, s0, s1, s2, s3);
    if (lane < 16) {
      f32x4 r;
      r[0] = fmaxf(s0 + bias[q * 4 + 0], 0.f);
      r[1] = fmaxf(s1 + bias[q * 4 + 1], 0.f);
      r[2] = fmaxf(s2 + bias[q * 4 + 2], 0.f);
      r[3] = fmaxf(s3 + bias[q * 4 + 3], 0.f);
      *(f32x4*)&rowbuf[ln][q * 4] = r;
    }
  }
  __syncthreads();

  // Phase 2: wave wid computes output channels [wid*16, wid*16+16).
  int lrow = lane & 15;
  int lk = (lane >> 4) * 8;
  f32x4 acc = {};
#pragma unroll
  for (int ks = 0; ks < 2; ++ks) {
    short8 a, bv;
#pragma unroll
    for (int j = 0; j < 8; ++j) a[j] = f2bf(rowbuf[lrow][ks * 32 + lk + j]);
#pragma unroll
    for (int j = 0; j < 8; ++j)
      bv[j] = f2bf(W[(size_t)(ks * 32 + lk + j) * 64 + wid * 16 + lrow]);
    acc = __builtin_amdgcn_mfma_f32_16x16x32_bf16(a, bv, acc, 0, 0, 0);
  }
  int crow = (lane >> 4) * 4;
#pragma unroll
  for (int r = 0; r < 4; ++r)
    outg[(size_t)(nbase + crow + r) * 64 + wid * 16 + lrow] = f2bf(acc[r]);
}

// ---------------------------------------------------------------------------
// Final agg + bias + ReLU (fp32 out). Wave per node (round-9 proven).
// ---------------------------------------------------------------------------
__global__ __launch_bounds__(256) void agg_final_kernel(
    const short* __restrict__ h, const int* __restrict__ row_ptr,
    const int* __restrict__ col, const float* __restrict__ bias,
    float* __restrict__ out, int n_nodes) {
  int node = blockIdx.x * 4 + (threadIdx.x >> 6);
  if (node >= n_nodes) return;
  int lane = threadIdx.x & 63;
  int slot = lane >> 4;
  int q = lane & 15;
  float s0, s1, s2, s3;
  agg_node(h, col, row_ptr[node], row_ptr[node + 1], slot, q, s0, s1, s2, s3);
  if (lane < 16) {
    float4 v;
    v.x = fmaxf(s0 + bias[q * 4 + 0], 0.f);
    v.y = fmaxf(s1 + bias[q * 4 + 1], 0.f);
    v.z = fmaxf(s2 + bias[q * 4 + 2], 0.f);
    v.w = fmaxf(s3 + bias[q * 4 + 3], 0.f);
    ((float4*)out)[(size_t)node * 16 + q] = v;
  }
}

extern "C" void kernel_launch(void* const* d_in, const int* in_sizes, int n_in,
                              void* d_out, int out_size, void* d_ws,
                              size_t ws_size, hipStream_t stream) {
  const float* x = (const float*)d_in[0];
  const int* src = (const int*)d_in[1];
  const int* dst = (const int*)d_in[2];
  const float* W1 = (const float*)d_in[3];
  const float* b1 = (const float*)d_in[4];
  const float* W2 = (const float*)d_in[5];
  const float* b2 = (const float*)d_in[6];
  const float* W3 = (const float*)d_in[7];
  const float* b3 = (const float*)d_in[8];
  float* out = (float*)d_out;

  const int N = N_NODES_C;
  const int E = N_EDGES_C;

  // Workspace layout (43 MB), as round 9.
  char* ws = (char*)d_ws;
  int* countsT = (int*)(ws + 0);
  int* btot = (int*)(ws + (1u << 20));
  int* bstart = (int*)(ws + (1u << 20) + (16u << 10));
  int* row_ptr = (int*)(ws + (2u << 20));
  unsigned* packed = (unsigned*)(ws + (3u << 20));
  int* col = (int*)(ws + (10u << 20));
  short* hA = (short*)(ws + (17u << 20));
  short* hB = (short*)(ws + (30u << 20));

  const int gemm_grid = (N + 63) / 64;  // 1563
  const int k1_grid = (NB_BUCK + 3) / 4;
  const int aggg_grid = N / 16;         // 6250
  const int aggf_grid = (N + 3) / 4;    // 25000

  // ---- CSR build; gemm1 overlapped with partition ----
  hist_kernel<<<NPB, 256, 0, stream>>>(dst, countsT);
  scan_buckets_kernel<<<k1_grid, 256, 0, stream>>>(countsT, btot);
  scan_btot_kernel<<<1, 1024, 0, stream>>>(btot, bstart);
  part_gemm1_kernel<<<NPB + gemm_grid, 256, 0, stream>>>(
      src, dst, countsT, bstart, packed, x, W1, hA, N);
  sort_bucket_kernel<<<NB_BUCK, 256, 0, stream>>>(packed, bstart, col, row_ptr,
                                                  N, E);

  // ---- Layer 1 agg fused with gemm2: hB = relu(agg(hA)+b1) @ W2 ----
  agg_gemm_kernel<<<aggg_grid, 256, 0, stream>>>(hA, row_ptr, col, b1, W2, hB,
                                                 N);
  // ---- Layer 2 agg fused with gemm3: hA = relu(agg(hB)+b2) @ W3 ----
  agg_gemm_kernel<<<aggg_grid, 256, 0, stream>>>(hB, row_ptr, col, b2, W3, hA,
                                                 N);
  // ---- Layer 3 final: out = relu(agg(hA)+b3) (fp32) ----
  agg_final_kernel<<<aggf_grid, 256, 0, stream>>>(hA, row_ptr, col, b3, out, N);
}